// Round 10
// baseline (280.437 us; speedup 1.0000x reference)
//
#include <hip/hip_runtime.h>

typedef unsigned int uint;
typedef unsigned short ushort;
typedef __attribute__((ext_vector_type(8))) short short8;
typedef __attribute__((ext_vector_type(4))) float f32x4;
typedef __attribute__((ext_vector_type(4))) uint uint4w;

#define T_LEN 32768
#define EMB 300
#define HID 256
#define NCOLS 4096

__device__ __forceinline__ ushort f2bf(float f) {
  uint u = __float_as_uint(f);
  return (ushort)((u + 0x7fffu + ((u >> 16) & 1u)) >> 16);
}
__device__ __forceinline__ float bf2f(ushort u) {
  return __uint_as_float(((uint)u) << 16);
}
__device__ __forceinline__ float sigm(float x) { return 1.f / (1.f + __expf(-x)); }
__device__ __forceinline__ float tanh_(float x) { return 2.f / (1.f + __expf(-2.f * x)) - 1.f; }

__device__ __forceinline__ void gload_lds16(const void* g, void* l) {
  __builtin_amdgcn_global_load_lds((const __attribute__((address_space(1))) void*)g,
                                   (__attribute__((address_space(3))) void*)l, 16, 0, 0);
}

// ---------------- prep: bf16 conversions + embedding gather ----------------
// Whh2[d][s(16)][c(4)][r(512)][e(8)] = whh_d[gp*512 + r][ks*32 + c*8 + e],  s = ks*2+gp
__global__ void prep_kernel(const float* __restrict__ emb,
                            const float* __restrict__ wihf, const float* __restrict__ whhf,
                            const float* __restrict__ bihf, const float* __restrict__ bhhf,
                            const float* __restrict__ wihb, const float* __restrict__ whhb,
                            const float* __restrict__ bihb, const float* __restrict__ bhhb,
                            const int* __restrict__ seq,
                            ushort* __restrict__ X, ushort* __restrict__ Wih,
                            ushort* __restrict__ Whh2, float* __restrict__ bias) {
  const int NX = T_LEN * 40;
  const int NWIH = 2048 * 40;
  const int NWHH = 2048 * 32;
  const int NB = 2048;
  const int total = NX + NWIH + NWHH + NB;
  for (int t = blockIdx.x * blockDim.x + threadIdx.x; t < total; t += gridDim.x * blockDim.x) {
    if (t < NX) {
      int r = t / 40, k8 = t % 40, k = k8 * 8;
      int col = r >> 3, j = r & 7;
      int tok = (col == 0) ? j : (col * 8 - 1 + j);
      const float* src = emb + (long)seq[tok] * EMB + k;
      alignas(16) ushort tmp[8];
#pragma unroll
      for (int i = 0; i < 8; ++i) tmp[i] = (k + i < EMB) ? f2bf(src[i]) : (ushort)0;
      *(uint4w*)(X + (long)r * 320 + k) = *(const uint4w*)tmp;
    } else if (t < NX + NWIH) {
      int t2 = t - NX;
      int n = t2 / 40, k8 = t2 % 40, k = k8 * 8;
      const float* src = ((n < 1024) ? wihf : wihb) + (long)(n & 1023) * EMB + k;
      alignas(16) ushort tmp[8];
#pragma unroll
      for (int i = 0; i < 8; ++i) tmp[i] = (k + i < EMB) ? f2bf(src[i]) : (ushort)0;
      *(uint4w*)(Wih + (long)n * 320 + k) = *(const uint4w*)tmp;
    } else if (t < NX + NWIH + NWHH) {
      int t3 = t - NX - NWIH;
      int n = t3 / 32, k8 = t3 % 32;
      int dd = n >> 10, rowg = n & 1023;
      int gp = rowg >> 9, rr = rowg & 511;
      int s = (k8 >> 2) * 2 + gp, c = k8 & 3;
      const float* src = ((dd == 0) ? whhf : whhb) + (long)rowg * HID + k8 * 8;
      alignas(16) ushort tmp[8];
#pragma unroll
      for (int i = 0; i < 8; ++i) tmp[i] = f2bf(src[i]);
      *(uint4w*)(Whh2 + ((((long)dd * 16 + s) * 4 + c) * 512 + rr) * 8) = *(const uint4w*)tmp;
    } else {
      int n = t - NX - NWIH - NWHH;
      bias[n] = (n < 1024) ? (bihf[n] + bhhf[n]) : (bihb[n - 1024] + bhhb[n - 1024]);
    }
  }
}

// ---------------- K1: xg = X @ Wih^T + bias  (M=32768,K=320,N=2048) ----------------
__global__ void gemm_xg_kernel(const ushort* __restrict__ X, const ushort* __restrict__ Wih,
                               const float* __restrict__ bias, ushort* __restrict__ xg) {
  __shared__ ushort a_lds[2][128 * 32];
  const int tid = threadIdx.x;
  const int lane = tid & 63, w = tid >> 6;
  const int wr = w >> 1, wc = w & 1;
  const int qrow = lane >> 4, ln = lane & 15;
  const int m0 = blockIdx.x * 128, n0 = blockIdx.y * 128;

  auto stage = [&](int buf, int kt) {
#pragma unroll
    for (int q = 0; q < 2; ++q) {
      int byteoff = w * 2048 + q * 1024 + lane * 16;
      int row = byteoff >> 6, koff = byteoff & 63;
      const char* src = (const char*)X + (long)(m0 + row) * 640 + kt * 64 + koff;
      void* dst = (char*)&a_lds[buf][0] + w * 2048 + q * 1024;
      gload_lds16(src, dst);
    }
  };

  const ushort* wb = Wih + (long)(n0 + wc * 64 + ln) * 320 + qrow * 8;
  auto loadB = [&](short8 (&dst)[4], int kt) {
#pragma unroll
    for (int nt = 0; nt < 4; ++nt)
      dst[nt] = *(const short8*)(wb + nt * 16 * 320 + kt * 32);
  };

  const f32x4 fzero = {0.f, 0.f, 0.f, 0.f};
  f32x4 acc[4][4];
#pragma unroll
  for (int i = 0; i < 4; ++i)
#pragma unroll
    for (int jj = 0; jj < 4; ++jj) acc[i][jj] = fzero;

  auto gemmK = [&](short8 (&b)[4], int buf) {
    short8 a[4];
#pragma unroll
    for (int rt = 0; rt < 4; ++rt)
      a[rt] = *(const short8*)&a_lds[buf][(wr * 64 + rt * 16 + ln) * 32 + qrow * 8];
#pragma unroll
    for (int rt = 0; rt < 4; ++rt)
#pragma unroll
      for (int nt = 0; nt < 4; ++nt)
        acc[rt][nt] = __builtin_amdgcn_mfma_f32_16x16x32_bf16(a[rt], b[nt], acc[rt][nt], 0, 0, 0);
  };

  short8 bA[4], bB[4];
  stage(0, 0);
  loadB(bA, 0);
#pragma unroll 1
  for (int kt2 = 0; kt2 < 5; ++kt2) {
    const int kt = kt2 * 2;
    __syncthreads();
    loadB(bB, kt + 1);
    __builtin_amdgcn_sched_barrier(0);
    if (kt < 9) stage(1, kt + 1);
    __builtin_amdgcn_sched_barrier(0);
    gemmK(bA, 0);
    __syncthreads();
    if (kt2 < 4) loadB(bA, kt + 2);
    __builtin_amdgcn_sched_barrier(0);
    if (kt + 2 < 10) stage(0, kt + 2);
    __builtin_amdgcn_sched_barrier(0);
    gemmK(bB, 1);
  }

  ushort* sbuf = &a_lds[0][0];
  float bv[4];
#pragma unroll
  for (int nt = 0; nt < 4; ++nt) bv[nt] = bias[n0 + wc * 64 + nt * 16 + ln];
#pragma unroll
  for (int R = 0; R < 4; ++R) {
    __syncthreads();
#pragma unroll
    for (int nt = 0; nt < 4; ++nt)
#pragma unroll
      for (int r = 0; r < 4; ++r)
        sbuf[(wr * 16 + qrow * 4 + r) * 128 + wc * 64 + nt * 16 + ln] = f2bf(acc[R][nt][r] + bv[nt]);
    __syncthreads();
#pragma unroll
    for (int p = 0; p < 2; ++p) {
      int row = p * 16 + (tid >> 4);
      int c0 = (tid & 15) * 8;
      uint4w v = *(uint4w*)&sbuf[row * 128 + c0];
      *(uint4w*)&xg[(long)(m0 + (row >> 4) * 64 + R * 16 + (row & 15)) * 2048 + n0 + c0] = v;
    }
  }
}

// ---------------- K2: fused masked LSTM recurrence ----------------
// grid 256 = {d} x {cg}; 32 cols/block; 512 threads (8 waves).
// Whh staged in 16 slices/step via global_load_lds into a 4-buffer ring, 3 slices
// in flight (vmcnt(8)). ks order ROTATED per block ((bid>>3)&7) so same-XCD CUs
// don't lockstep-read the same L2 lines (bank-camping fix).
__global__ __launch_bounds__(512) void lstm_kernel(const ushort* __restrict__ xg,
                                                   const ushort* __restrict__ Whh2,
                                                   float* __restrict__ out) {
  __shared__ ushort h_lds[32][264];
  __shared__ alignas(16) char b_lds[4][32768];      // B slice ring (128 KB)
  const int tid = threadIdx.x;
  const int lane = tid & 63, w = tid >> 6;
  const int qrow = lane >> 4, ln = lane & 15;
  const int bid = blockIdx.x;
  const int d = bid >> 7, cg = bid & 127;
  const int rot = (bid >> 3) & 7;   // bid&7 = XCD id -> >>3 decorrelates within an XCD

  float c_st[2][2][4], h_st[2][2][4];
#pragma unroll
  for (int rt = 0; rt < 2; ++rt)
#pragma unroll
    for (int q = 0; q < 2; ++q)
#pragma unroll
      for (int r = 0; r < 4; ++r) { c_st[rt][q][r] = 0.f; h_st[rt][q][r] = 0.f; }

  // stage slice s (32 KB contiguous) into b_lds[bufi]; 4 DMA ops/wave
  auto stageB = [&](int s, int bufi) {
    const char* src = (const char*)Whh2 + (((long)(d * 16 + s)) << 15) + w * 4096 + lane * 16;
    char* dst = &b_lds[bufi][0] + w * 4096;
#pragma unroll
    for (int q2 = 0; q2 < 4; ++q2) gload_lds16(src + q2 * 1024, dst + q2 * 1024);
  };

  const f32x4 fzero = {0.f, 0.f, 0.f, 0.f};

#pragma unroll 1
  for (int it = 0; it < 8; ++it) {
    const int j = d ? (7 - it) : it;
    // LDS-only barrier: h_lds(it-1) visible; prologue stages stay in flight
    asm volatile("s_waitcnt lgkmcnt(0)" ::: "memory");
    __builtin_amdgcn_s_barrier();
    asm volatile("" ::: "memory");

    f32x4 acc[4][2][2];
#pragma unroll
    for (int g = 0; g < 4; ++g)
#pragma unroll
      for (int q = 0; q < 2; ++q)
#pragma unroll
        for (int rt = 0; rt < 2; ++rt) acc[g][q][rt] = fzero;

    if (it > 0) {  // h==0 at it==0, skip GEMM
#pragma unroll
      for (int kk = 0; kk < 8; ++kk) {
        const int ks = (rot + kk) & 7;
        short8 a0 = *(const short8*)&h_lds[ln][ks * 32 + qrow * 8];
        short8 a1 = *(const short8*)&h_lds[16 + ln][ks * 32 + qrow * 8];
#pragma unroll
        for (int gp = 0; gp < 2; ++gp) {
          const int p = kk * 2 + gp;            // static position 0..15
          if (p == 15)      { asm volatile("s_waitcnt vmcnt(0)" ::: "memory"); }
          else if (p == 14) { asm volatile("s_waitcnt vmcnt(4)" ::: "memory"); }
          else              { asm volatile("s_waitcnt vmcnt(8)" ::: "memory"); }
          __builtin_amdgcn_s_barrier();
          asm volatile("" ::: "memory");
          if (p <= 12) {
            // stage position p+3: gp==0 -> (kk+1, gp'=1); gp==1 -> (kk+2, gp'=0)
            const int sNext = (gp == 0) ? (((rot + kk + 1) & 7) * 2 + 1)
                                        : (((rot + kk + 2) & 7) * 2 + 0);
            stageB(sNext, (p + 3) & 3);
          }
          const char* bb = &b_lds[p & 3][0];
#pragma unroll
          for (int gi = 0; gi < 2; ++gi)
#pragma unroll
            for (int q = 0; q < 2; ++q) {
              short8 b = *(const short8*)(bb + qrow * 8192 + (gi * 256 + w * 32 + q * 16 + ln) * 16);
              const int g = gp * 2 + gi;
              acc[g][q][0] = __builtin_amdgcn_mfma_f32_16x16x32_bf16(a0, b, acc[g][q][0], 0, 0, 0);
              acc[g][q][1] = __builtin_amdgcn_mfma_f32_16x16x32_bf16(a1, b, acc[g][q][1], 0, 0, 0);
            }
        }
      }
    }

    // per-lane xg loads for this step
    const ushort* xgb = xg + (long)(cg * 256 + j) * 2048 + qrow * 65536 + d * 1024 + w * 32 + ln;
    ushort xv[2][2][4][4];
#pragma unroll
    for (int rt = 0; rt < 2; ++rt)
#pragma unroll
      for (int q = 0; q < 2; ++q)
#pragma unroll
        for (int r = 0; r < 4; ++r)
#pragma unroll
          for (int g = 0; g < 4; ++g)
            xv[rt][q][r][g] = xgb[(long)rt * 262144 + r * 16384 + g * 256 + q * 16];

    // GEMM <-> cell hazard barrier (LDS only)
    asm volatile("s_waitcnt lgkmcnt(0)" ::: "memory");
    __builtin_amdgcn_s_barrier();
    asm volatile("" ::: "memory");

    const bool mstep = d ? (it == 0) : (it == 7);
#pragma unroll
    for (int rt = 0; rt < 2; ++rt)
#pragma unroll
      for (int q = 0; q < 2; ++q)
#pragma unroll
        for (int r = 0; r < 4; ++r) {
          int cc = rt * 16 + qrow * 4 + r;
          int hid = w * 32 + q * 16 + ln;
          float pi = acc[0][q][rt][r] + bf2f(xv[rt][q][r][0]);
          float pf = acc[1][q][rt][r] + bf2f(xv[rt][q][r][1]);
          float pg = acc[2][q][rt][r] + bf2f(xv[rt][q][r][2]);
          float po = acc[3][q][rt][r] + bf2f(xv[rt][q][r][3]);
          float cn = sigm(pf) * c_st[rt][q][r] + sigm(pi) * tanh_(pg);
          float hn = sigm(po) * tanh_(cn);
          bool skip = mstep && (cg == 0) && (cc == 0);
          if (!skip) { c_st[rt][q][r] = cn; h_st[rt][q][r] = hn; }
          h_lds[cc][hid] = f2bf(h_st[rt][q][r]);
        }

    // prologue for next step: stage positions 0,1,2 (rotated) into bufs 0,1,2
    if (it < 7) {
      stageB((rot & 7) * 2 + 0, 0);
      stageB((rot & 7) * 2 + 1, 1);
      stageB(((rot + 1) & 7) * 2 + 0, 2);
    }
  }

#pragma unroll
  for (int rt = 0; rt < 2; ++rt)
#pragma unroll
    for (int q = 0; q < 2; ++q)
#pragma unroll
      for (int r = 0; r < 4; ++r) {
        int cc = rt * 16 + qrow * 4 + r;
        int hid = w * 32 + q * 16 + ln;
        out[(long)(cg * 32 + cc) * 512 + d * 256 + hid] = h_st[rt][q][r];
      }
}

extern "C" void kernel_launch(void* const* d_in, const int* in_sizes, int n_in,
                              void* d_out, int out_size, void* d_ws, size_t ws_size,
                              hipStream_t stream) {
  const float* emb  = (const float*)d_in[0];
  const float* wihf = (const float*)d_in[1];
  const float* whhf = (const float*)d_in[2];
  const float* bihf = (const float*)d_in[3];
  const float* bhhf = (const float*)d_in[4];
  const float* wihb = (const float*)d_in[5];
  const float* whhb = (const float*)d_in[6];
  const float* bihb = (const float*)d_in[7];
  const float* bhhb = (const float*)d_in[8];
  const int*   seq  = (const int*)d_in[9];
  float* out = (float*)d_out;

  char* ws = (char*)d_ws;
  // ws layout (bytes): xg 134217728 | X 20971520 | Wih 1310720 | Whh2 1048576 | bias 8192
  ushort* xg   = (ushort*)(ws);
  ushort* X    = (ushort*)(ws + 134217728);
  ushort* Wih  = (ushort*)(ws + 155189248);
  ushort* Whh2 = (ushort*)(ws + 156499968);
  float*  bias = (float*)(ws + 157548544);

  prep_kernel<<<dim3(1024), dim3(256), 0, stream>>>(emb, wihf, whhf, bihf, bhhf,
                                                    wihb, whhb, bihb, bhhb, seq,
                                                    X, Wih, Whh2, bias);
  gemm_xg_kernel<<<dim3(256, 16), dim3(256), 0, stream>>>(X, Wih, bias, xg);
  lstm_kernel<<<dim3(256), dim3(512), 0, stream>>>(xg, Whh2, out);
}